// Round 20
// baseline (37.769 us; speedup 1.0000x reference)
//
#include <hip/hip_runtime.h>
#include <stdint.h>

typedef __attribute__((ext_vector_type(4)))  int   i32x4;
typedef __attribute__((ext_vector_type(8)))  int   i32x8;
typedef __attribute__((ext_vector_type(16))) float f32x16;

#define NROWS 4096
#define RB    512      // bytes per fp4 row (1024 elems * 0.5B)
#define NST   8        // K-steps of 64 bytes (128 elements)
#define NB    32       // 128-row panels
#define NBLK  528      // NB*(NB+1)/2 triangular 128x128 tiles
#define COS_EPS 1e-8f
#define SCL   0x7F7F7F7F   // E8M0 = 127 -> scale 1.0
#define FP4   4            // f8f6f4 format code E2M1

__device__ __forceinline__ void gload16(const uint8_t* g, uint8_t* l) {
  __builtin_amdgcn_global_load_lds(
      (const __attribute__((address_space(1))) uint32_t*)g,
      (__attribute__((address_space(3))) uint32_t*)l, 16, 0, 0);
}

__device__ __forceinline__ i32x8 ext8(i32x4 lo) {
  i32x8 r;
  r[0] = lo[0]; r[1] = lo[1]; r[2] = lo[2]; r[3] = lo[3];
  r[4] = 0; r[5] = 0; r[6] = 0; r[7] = 0;
  return r;
}

// nearest e2m1 code for |x| (codes 0..7 -> {0,.5,1,1.5,2,3,4,6})
__device__ __forceinline__ uint32_t fp4q(float x) {
  const float a = fabsf(x);
  uint32_t c;
  if      (a < 0.25f) c = 0;
  else if (a < 0.75f) c = 1;
  else if (a < 1.25f) c = 2;
  else if (a < 1.75f) c = 3;
  else if (a < 2.5f)  c = 4;
  else if (a < 3.5f)  c = 5;
  else if (a < 5.0f)  c = 6;
  else                c = 7;
  return c | (x < 0.f ? 8u : 0u);
}

// ---------------- prep: sq, 1/norm, fp4 e2m1 copy, zero out ----------------
extern "C" __global__ void __launch_bounds__(256) prep_kernel(
    const float* __restrict__ F, uint8_t* __restrict__ Fb,
    float* __restrict__ sq, float* __restrict__ rn, float* __restrict__ out) {
  if (blockIdx.x == 0 && threadIdx.x == 0) out[0] = 0.f;   // atomic target
  const int row  = blockIdx.x * 4 + (threadIdx.x >> 6);
  const int lane = threadIdx.x & 63;
  const float4* src = (const float4*)(F + (size_t)row * 1024 + lane * 16);
  float4 v[4];
#pragma unroll
  for (int i = 0; i < 4; ++i) v[i] = src[i];
  float s = 0.f;
#pragma unroll
  for (int i = 0; i < 4; ++i)
    s += v[i].x * v[i].x + v[i].y * v[i].y + v[i].z * v[i].z + v[i].w * v[i].w;
  uint32_t b[2] = {0, 0};
#pragma unroll
  for (int i = 0; i < 4; ++i) {
    const uint32_t n0 = fp4q(v[i].x), n1 = fp4q(v[i].y);
    const uint32_t n2 = fp4q(v[i].z), n3 = fp4q(v[i].w);
    const uint32_t byte2 = (n0 | (n1 << 4)) | ((n2 | (n3 << 4)) << 8);
    b[i >> 1] |= byte2 << ((i & 1) * 16);
  }
  *(uint2*)(Fb + (size_t)row * RB + lane * 8) = make_uint2(b[0], b[1]);
#pragma unroll
  for (int off = 32; off; off >>= 1) s += __shfl_down(s, off);
  if (lane == 0) {
    sq[row] = s;
    rn[row] = 1.0f / fmaxf(sqrtf(s), COS_EPS);
  }
}

// ---------------- fused gram: FP4, triangle 128x128, FAT K-steps -----------
// R14/R17-verified core with K-step doubled to 128 elements (64 B/row):
// 8 steps; per step {8 ds_read_b128 | 4 gload_lds (stage s+2) | 8 MFMA
// (setprio) | ONE vmcnt(4) | ONE barrier}. Halves total sync count while
// holding tile/wave geometry, ring depth, and frag-major 0-conflict LDS
// fixed. Slot = 16 KB (A 8K: [ksub][fgrp][lane*16B]; B 8K at +8192);
// ring-3 = 48 KB. Fused atomic final reduce (R19-verified).
extern "C" __global__ void __launch_bounds__(256, 3) gram_kernel(
    const uint8_t* __restrict__ Fb, const float* __restrict__ sq,
    const float* __restrict__ rn, const int* __restrict__ y,
    float* __restrict__ out) {
  __shared__ __align__(16) uint8_t lds[3][16384];
  __shared__ float wsum[4];

  // XCD-chunked bijection (528 = 8*66) + triangular staircase decode
  int s0 = (int)(blockIdx.x & 7) * 66 + (int)(blockIdx.x >> 3);
  int bi = 0, rem0 = s0;
  while (rem0 >= NB - bi) { rem0 -= NB - bi; ++bi; }
  const int bj = bi + rem0;
  const bool diag = (bi == bj);

  const int tid  = threadIdx.x;
  const int lane = tid & 63;
  const int wid  = tid >> 6;
  const int wr   = wid >> 1;      // 0..1 : 64-row group
  const int wc   = wid & 1;       // 0..1 : 64-col group
  const int kg   = lane >> 5;
  const int r32  = lane & 31;

  // staging: thread tid stages granule (fgrp=tid>>6, l=tid&63) for both
  // ksubs of A and B: row = (tid>>6)*32 + (tid&31), bytes (l>>5)*16 (+32).
  const int srow = ((tid >> 6) << 5) + (tid & 31);     // 0..127
  const int scol = ((tid >> 5) & 1) * 16;
  const uint8_t* gA = Fb + (size_t)(bi * 128 + srow) * RB + scol;
  const uint8_t* gB = Fb + (size_t)(bj * 128 + srow) * RB + scol;
  uint8_t* ldsT = &lds[0][0] + tid * 16;

  // fragment read offsets (ksub=0; ksub=1 adds +4096)
  const int oA0 = (wr * 2 + 0) * 1024 + lane * 16;
  const int oA1 = (wr * 2 + 1) * 1024 + lane * 16;
  const int oB0 = 8192 + (wc * 2 + 0) * 1024 + lane * 16;
  const int oB1 = 8192 + (wc * 2 + 1) * 1024 + lane * 16;

  f32x16 acc[2][2] = {};

#define STAGE(s2) do {                                                      \
    const int _sl = (s2) % 3;                                               \
    gload16(gA + (s2) * 64,      ldsT + _sl * 16384);                       \
    gload16(gA + (s2) * 64 + 32, ldsT + _sl * 16384 + 4096);                \
    gload16(gB + (s2) * 64,      ldsT + _sl * 16384 + 8192);                \
    gload16(gB + (s2) * 64 + 32, ldsT + _sl * 16384 + 12288);               \
  } while (0)

#define MM(mt, nb, a, b)                                                    \
    acc[mt][nb] = __builtin_amdgcn_mfma_scale_f32_32x32x64_f8f6f4(          \
        a, b, acc[mt][nb], FP4, FP4, 0, SCL, 0, SCL)

  // prologue: steps 0,1 in flight (8 loads); wait step 0 (leave 4)
  STAGE(0); STAGE(1);
  asm volatile("s_waitcnt vmcnt(4)");
  __builtin_amdgcn_s_barrier();
  __builtin_amdgcn_sched_barrier(0);

#pragma unroll 1
  for (int s = 0; s < NST; ++s) {
    const uint8_t* sl = &lds[0][0] + (s % 3) * 16384;

    const i32x8 A0a = ext8(*(const i32x4*)(sl + oA0));
    const i32x8 A1a = ext8(*(const i32x4*)(sl + oA1));
    const i32x8 B0a = ext8(*(const i32x4*)(sl + oB0));
    const i32x8 B1a = ext8(*(const i32x4*)(sl + oB1));
    const i32x8 A0b = ext8(*(const i32x4*)(sl + 4096 + oA0));
    const i32x8 A1b = ext8(*(const i32x4*)(sl + 4096 + oA1));
    const i32x8 B0b = ext8(*(const i32x4*)(sl + 4096 + oB0));
    const i32x8 B1b = ext8(*(const i32x4*)(sl + 4096 + oB1));

    if (s + 2 < NST) STAGE(s + 2);   // writes slot (s-1)%3: readers drained

    __builtin_amdgcn_s_setprio(1);
    MM(0, 0, A0a, B0a); MM(0, 1, A0a, B1a);
    MM(1, 0, A1a, B0a); MM(1, 1, A1a, B1a);
    MM(0, 0, A0b, B0b); MM(0, 1, A0b, B1b);
    MM(1, 0, A1b, B0b); MM(1, 1, A1b, B1b);
    __builtin_amdgcn_s_setprio(0);

    if (s < NST - 2)       asm volatile("s_waitcnt vmcnt(4)");  // s+1 landed
    else if (s == NST - 2) asm volatile("s_waitcnt vmcnt(0)");
    if (s < NST - 1) {
      __builtin_amdgcn_s_barrier();
      __builtin_amdgcn_sched_barrier(0);   // next-iter ds_reads stay below
    }
  }

#undef STAGE
#undef MM

  // ---------- epilogue: triangle weights (32x32 C/D layout) ----------
  float sqc[2], rnc[2];
  int   yc[2];
#pragma unroll
  for (int nb = 0; nb < 2; ++nb) {
    const int gj = bj * 128 + wc * 64 + nb * 32 + r32;
    sqc[nb] = sq[gj]; rnc[nb] = rn[gj]; yc[nb] = y[gj];
  }
  float lsum = 0.f;
#pragma unroll
  for (int mt = 0; mt < 2; ++mt) {
#pragma unroll
    for (int e = 0; e < 16; ++e) {
      const int gi = bi * 128 + wr * 64 + mt * 32 + (e & 3) + 8 * (e >> 2) + 4 * kg;
      const float sqi = sq[gi], rni = rn[gi];
      const int yi = y[gi];
#pragma unroll
      for (int nb = 0; nb < 2; ++nb) {
        const int gj = bj * 128 + wc * 64 + nb * 32 + r32;
        const float g  = acc[mt][nb][e];
        const float d2 = sqi + sqc[nb] - 2.0f * g;
        const float dist = d2 > 0.f ? sqrtf(d2) : 0.f;
        const float sim  = g * rni * rnc[nb];
        const float sgn  = (yi == yc[nb]) ? 1.0f : -1.0f;
        float wgt;
        if (diag) wgt = (gj > gi) ? 2.0f : ((gj == gi) ? 1.0f : 0.0f);
        else      wgt = 2.0f;
        lsum += wgt * sgn * (dist - sim);
      }
    }
  }
#pragma unroll
  for (int off = 32; off; off >>= 1) lsum += __shfl_down(lsum, off);
  if (lane == 0) wsum[wid] = lsum;
  __syncthreads();
  if (tid == 0)
    atomicAdd(out, wsum[0] + wsum[1] + wsum[2] + wsum[3]);
}

extern "C" void kernel_launch(void* const* d_in, const int* in_sizes, int n_in,
                              void* d_out, int out_size, void* d_ws, size_t ws_size,
                              hipStream_t stream) {
  const float* F = (const float*)d_in[0];
  const int*   y = (const int*)d_in[1];
  float* out = (float*)d_out;

  uint8_t* Fb = (uint8_t*)d_ws;                               // 2 MB fp4
  float*  sq = (float*)((char*)d_ws + (size_t)NROWS * RB);
  float*  rn = sq + NROWS;

  prep_kernel<<<NROWS / 4, 256, 0, stream>>>(F, Fb, sq, rn, out);
  gram_kernel<<<NBLK, 256, 0, stream>>>(Fb, sq, rn, y, out);
}

// Round 21
// 35.316 us; speedup vs baseline: 1.0695x; 1.0695x over previous
//
#include <hip/hip_runtime.h>
#include <stdint.h>

typedef __attribute__((ext_vector_type(4)))  int   i32x4;
typedef __attribute__((ext_vector_type(8)))  int   i32x8;
typedef __attribute__((ext_vector_type(16))) float f32x16;

#define NROWS 4096
#define DDIM  1024     // bytes per fp8 row
#define NKT   16       // K-tiles of 64 bytes
#define NB    32       // 128-row panels
#define NBLK  528      // NB*(NB+1)/2 triangular 128x128 tiles
#define COS_EPS 1e-8f
#define SCL   0x7F7F7F7F   // E8M0 = 127 -> scale 1.0

__device__ __forceinline__ void gload16(const uint8_t* g, uint8_t* l) {
  __builtin_amdgcn_global_load_lds(
      (const __attribute__((address_space(1))) uint32_t*)g,
      (__attribute__((address_space(3))) uint32_t*)l, 16, 0, 0);
}

__device__ __forceinline__ i32x8 cat8(i32x4 lo, i32x4 hi) {
  i32x8 r;
  r[0] = lo[0]; r[1] = lo[1]; r[2] = lo[2]; r[3] = lo[3];
  r[4] = hi[0]; r[5] = hi[1]; r[6] = hi[2]; r[7] = hi[3];
  return r;
}

// ---------------- prep: sq, 1/norm, fp8 e4m3 copy, zero out ----------------
extern "C" __global__ void __launch_bounds__(256) prep_kernel(
    const float* __restrict__ F, uint8_t* __restrict__ Fb,
    float* __restrict__ sq, float* __restrict__ rn, float* __restrict__ out) {
  if (blockIdx.x == 0 && threadIdx.x == 0) out[0] = 0.f;   // atomic target
  const int row  = blockIdx.x * 4 + (threadIdx.x >> 6);
  const int lane = threadIdx.x & 63;
  const float4* src = (const float4*)(F + (size_t)row * DDIM + lane * 16);
  float4 v[4];
#pragma unroll
  for (int i = 0; i < 4; ++i) v[i] = src[i];
  float s = 0.f;
#pragma unroll
  for (int i = 0; i < 4; ++i)
    s += v[i].x * v[i].x + v[i].y * v[i].y + v[i].z * v[i].z + v[i].w * v[i].w;
  uint32_t d[4];
#pragma unroll
  for (int i = 0; i < 4; ++i) {
    int w = __builtin_amdgcn_cvt_pk_fp8_f32(v[i].x, v[i].y, 0, false);
    w = __builtin_amdgcn_cvt_pk_fp8_f32(v[i].z, v[i].w, w, true);
    d[i] = (uint32_t)w;
  }
  *(uint4*)(Fb + (size_t)row * DDIM + lane * 16) = make_uint4(d[0], d[1], d[2], d[3]);
#pragma unroll
  for (int off = 32; off; off >>= 1) s += __shfl_down(s, off);
  if (lane == 0) {
    sq[row] = s;
    rn[row] = 1.0f / fmaxf(sqrtf(s), COS_EPS);
  }
}

// ---------------- fused gram: fp8 MX, TRIANGULAR 128x128 (R14 exact) -------
// 528 blocks (bi<=bj), 256 thr = 4 waves (2M x 2N), wave = 64x64 out.
// 3-slot LDS ring (48 KB), stage kt+2, counted vmcnt(4), one barrier/K-tile.
// Row-pair LDS map (R14): full 64B-line coverage per gload instruction
// (the staging property that R15 showed is the real lever). NO setprio
// (the single untested toggle). Fused atomic final reduce (R19-verified).
extern "C" __global__ void __launch_bounds__(256, 3) gram_kernel(
    const uint8_t* __restrict__ Fb, const float* __restrict__ sq,
    const float* __restrict__ rn, const int* __restrict__ y,
    float* __restrict__ out) {
  __shared__ __align__(16) uint8_t As[3][8192];   // 128 rows x 64B per slot
  __shared__ __align__(16) uint8_t Bs[3][8192];
  __shared__ float wsum[4];

  // XCD-chunked bijection (528 = 8*66) + triangular staircase decode
  int s = (int)(blockIdx.x & 7) * 66 + (int)(blockIdx.x >> 3);
  int bi = 0, rem0 = s;
  while (rem0 >= NB - bi) { rem0 -= NB - bi; ++bi; }
  const int bj = bi + rem0;
  const bool diag = (bi == bj);

  const int tid  = threadIdx.x;
  const int lane = tid & 63;
  const int wid  = tid >> 6;
  const int wr   = wid >> 1;      // 0..1 : 64-row group
  const int wc   = wid & 1;       // 0..1 : 64-col group
  const int kg   = lane >> 5;
  const int r32  = lane & 31;

  // staging source decode (inverse of row-pair + granule-XOR LDS map)
  const int hc   = (tid & 7) ^ ((tid >> 3) & 7);
  const int srow = 2 * (tid >> 3) + ((hc >> 2) & 1);   // 0..63
  const int scol = (hc & 3) * 16;
  const uint8_t* gA = Fb + (size_t)(bi * 128 + srow) * DDIM + scol;
  const uint8_t* gB = Fb + (size_t)(bj * 128 + srow) * DDIM + scol;
  uint8_t* ldsA = &As[0][0] + tid * 16;
  uint8_t* ldsB = &Bs[0][0] + tid * 16;

  // fragment read offsets (lo granule; hi = lo ^ 16)
  int offA[2], offB[2];
#pragma unroll
  for (int mt = 0; mt < 2; ++mt) {
    const int R = wr * 64 + mt * 32 + r32;
    const int u = R >> 1, h = R & 1;
    offA[mt] = u * 128 + (((h << 2) + 2 * kg) ^ (u & 7)) * 16;
  }
#pragma unroll
  for (int nb = 0; nb < 2; ++nb) {
    const int R = wc * 64 + nb * 32 + r32;
    const int u = R >> 1, h = R & 1;
    offB[nb] = u * 128 + (((h << 2) + 2 * kg) ^ (u & 7)) * 16;
  }

  f32x16 acc[2][2] = {};

#define STAGE(kt2) do {                                                     \
    const int _sl = (kt2) % 3;                                              \
    const uint8_t* _a = gA + (kt2) * 64;                                    \
    const uint8_t* _b = gB + (kt2) * 64;                                    \
    gload16(_a,                      ldsA + _sl * 8192);                    \
    gload16(_a + (size_t)64 * DDIM,  ldsA + _sl * 8192 + 4096);             \
    gload16(_b,                      ldsB + _sl * 8192);                    \
    gload16(_b + (size_t)64 * DDIM,  ldsB + _sl * 8192 + 4096);             \
  } while (0)

  // prologue: K-tiles 0,1 in flight; wait tile 0; publish
  STAGE(0); STAGE(1);
  asm volatile("s_waitcnt vmcnt(4)");
  __builtin_amdgcn_s_barrier();
  __builtin_amdgcn_sched_barrier(0);

#pragma unroll 1
  for (int kt = 0; kt < NKT; ++kt) {
    const uint8_t* sa = &As[0][0] + (kt % 3) * 8192;
    const uint8_t* sb = &Bs[0][0] + (kt % 3) * 8192;

    const i32x8 A0 = cat8(*(const i32x4*)(sa + offA[0]),
                          *(const i32x4*)(sa + (offA[0] ^ 16)));
    const i32x8 A1 = cat8(*(const i32x4*)(sa + offA[1]),
                          *(const i32x4*)(sa + (offA[1] ^ 16)));
    const i32x8 B0 = cat8(*(const i32x4*)(sb + offB[0]),
                          *(const i32x4*)(sb + (offB[0] ^ 16)));
    const i32x8 B1 = cat8(*(const i32x4*)(sb + offB[1]),
                          *(const i32x4*)(sb + (offB[1] ^ 16)));

    if (kt + 2 < NKT) STAGE(kt + 2);

    acc[0][0] = __builtin_amdgcn_mfma_scale_f32_32x32x64_f8f6f4(
        A0, B0, acc[0][0], 0, 0, 0, SCL, 0, SCL);
    acc[0][1] = __builtin_amdgcn_mfma_scale_f32_32x32x64_f8f6f4(
        A0, B1, acc[0][1], 0, 0, 0, SCL, 0, SCL);
    acc[1][0] = __builtin_amdgcn_mfma_scale_f32_32x32x64_f8f6f4(
        A1, B0, acc[1][0], 0, 0, 0, SCL, 0, SCL);
    acc[1][1] = __builtin_amdgcn_mfma_scale_f32_32x32x64_f8f6f4(
        A1, B1, acc[1][1], 0, 0, 0, SCL, 0, SCL);

    if (kt + 2 < NKT)       asm volatile("s_waitcnt vmcnt(4)");  // kt+1 landed
    else if (kt == NKT - 2) asm volatile("s_waitcnt vmcnt(0)");
    if (kt < NKT - 1) {
      __builtin_amdgcn_s_barrier();
      __builtin_amdgcn_sched_barrier(0);   // next-iter ds_reads stay below
    }
  }

#undef STAGE

  // ---------- epilogue: triangle weights ----------
  float sqc[2], rnc[2];
  int   yc[2];
#pragma unroll
  for (int nb = 0; nb < 2; ++nb) {
    const int gj = bj * 128 + wc * 64 + nb * 32 + r32;
    sqc[nb] = sq[gj]; rnc[nb] = rn[gj]; yc[nb] = y[gj];
  }
  float lsum = 0.f;
#pragma unroll
  for (int mt = 0; mt < 2; ++mt) {
#pragma unroll
    for (int e = 0; e < 16; ++e) {
      const int gi = bi * 128 + wr * 64 + mt * 32 + (e & 3) + 8 * (e >> 2) + 4 * kg;
      const float sqi = sq[gi], rni = rn[gi];
      const int yi = y[gi];
#pragma unroll
      for (int nb = 0; nb < 2; ++nb) {
        const int gj = bj * 128 + wc * 64 + nb * 32 + r32;
        const float g  = acc[mt][nb][e];
        const float d2 = sqi + sqc[nb] - 2.0f * g;
        const float dist = d2 > 0.f ? sqrtf(d2) : 0.f;
        const float sim  = g * rni * rnc[nb];
        const float sgn  = (yi == yc[nb]) ? 1.0f : -1.0f;
        float wgt;
        if (diag) wgt = (gj > gi) ? 2.0f : ((gj == gi) ? 1.0f : 0.0f);
        else      wgt = 2.0f;
        lsum += wgt * sgn * (dist - sim);
      }
    }
  }
#pragma unroll
  for (int off = 32; off; off >>= 1) lsum += __shfl_down(lsum, off);
  if (lane == 0) wsum[wid] = lsum;
  __syncthreads();
  if (tid == 0)
    atomicAdd(out, wsum[0] + wsum[1] + wsum[2] + wsum[3]);
}

extern "C" void kernel_launch(void* const* d_in, const int* in_sizes, int n_in,
                              void* d_out, int out_size, void* d_ws, size_t ws_size,
                              hipStream_t stream) {
  const float* F = (const float*)d_in[0];
  const int*   y = (const int*)d_in[1];
  float* out = (float*)d_out;

  uint8_t* Fb = (uint8_t*)d_ws;                               // 4 MB fp8
  float*  sq = (float*)((char*)d_ws + (size_t)NROWS * DDIM);
  float*  rn = sq + NROWS;

  prep_kernel<<<NROWS / 4, 256, 0, stream>>>(F, Fb, sq, rn, out);
  gram_kernel<<<NBLK, 256, 0, stream>>>(Fb, sq, rn, y, out);
}

// Round 22
// 34.173 us; speedup vs baseline: 1.1052x; 1.0335x over previous
//
#include <hip/hip_runtime.h>
#include <stdint.h>

typedef __attribute__((ext_vector_type(4)))  int   i32x4;
typedef __attribute__((ext_vector_type(8)))  int   i32x8;
typedef __attribute__((ext_vector_type(16))) float f32x16;

#define NROWS 4096
#define DDIM  1024     // bytes per fp8 row
#define NKT   16       // K-tiles of 64 bytes
#define NB    32       // 128-row panels
#define NBLK  528      // NB*(NB+1)/2 triangular 128x128 tiles
#define COS_EPS 1e-8f
#define SCL   0x7F7F7F7F   // E8M0 = 127 -> scale 1.0

__device__ __forceinline__ void gload16(const uint8_t* g, uint8_t* l) {
  __builtin_amdgcn_global_load_lds(
      (const __attribute__((address_space(1))) uint32_t*)g,
      (__attribute__((address_space(3))) uint32_t*)l, 16, 0, 0);
}

__device__ __forceinline__ i32x8 cat8(i32x4 lo, i32x4 hi) {
  i32x8 r;
  r[0] = lo[0]; r[1] = lo[1]; r[2] = lo[2]; r[3] = lo[3];
  r[4] = hi[0]; r[5] = hi[1]; r[6] = hi[2]; r[7] = hi[3];
  return r;
}

// ---------------- prep: sq, 1/norm, fp8 e4m3 copy, zero out ----------------
extern "C" __global__ void __launch_bounds__(256) prep_kernel(
    const float* __restrict__ F, uint8_t* __restrict__ Fb,
    float* __restrict__ sq, float* __restrict__ rn, float* __restrict__ out) {
  if (blockIdx.x == 0 && threadIdx.x == 0) out[0] = 0.f;   // atomic target
  const int row  = blockIdx.x * 4 + (threadIdx.x >> 6);
  const int lane = threadIdx.x & 63;
  const float4* src = (const float4*)(F + (size_t)row * DDIM + lane * 16);
  float4 v[4];
#pragma unroll
  for (int i = 0; i < 4; ++i) v[i] = src[i];
  float s = 0.f;
#pragma unroll
  for (int i = 0; i < 4; ++i)
    s += v[i].x * v[i].x + v[i].y * v[i].y + v[i].z * v[i].z + v[i].w * v[i].w;
  uint32_t d[4];
#pragma unroll
  for (int i = 0; i < 4; ++i) {
    int w = __builtin_amdgcn_cvt_pk_fp8_f32(v[i].x, v[i].y, 0, false);
    w = __builtin_amdgcn_cvt_pk_fp8_f32(v[i].z, v[i].w, w, true);
    d[i] = (uint32_t)w;
  }
  *(uint4*)(Fb + (size_t)row * DDIM + lane * 16) = make_uint4(d[0], d[1], d[2], d[3]);
#pragma unroll
  for (int off = 32; off; off >>= 1) s += __shfl_down(s, off);
  if (lane == 0) {
    sq[row] = s;
    rn[row] = 1.0f / fmaxf(sqrtf(s), COS_EPS);
  }
}

// ---------------- fused gram: fp8 MX triangle 128x128, 8 x 64x32 waves -----
// R14 pipeline and LDS map EXACTLY, but 512 threads = 8 waves (2M x 4N),
// wave = 64x32 out (acc 2 x f32x16 = 32 regs). Same 48 KB 3-slot ring, same
// row-pair staging (1 gload/operand/thread now covers all 128 rows), counted
// vmcnt(2), one barrier/K-tile. Doubles resident waves/CU: 8 -> 16.
extern "C" __global__ void __launch_bounds__(512, 4) gram_kernel(
    const uint8_t* __restrict__ Fb, const float* __restrict__ sq,
    const float* __restrict__ rn, const int* __restrict__ y,
    float* __restrict__ out) {
  __shared__ __align__(16) uint8_t As[3][8192];   // 128 rows x 64B per slot
  __shared__ __align__(16) uint8_t Bs[3][8192];
  __shared__ float wsum[8];

  // XCD-chunked bijection (528 = 8*66) + triangular staircase decode
  int s = (int)(blockIdx.x & 7) * 66 + (int)(blockIdx.x >> 3);
  int bi = 0, rem0 = s;
  while (rem0 >= NB - bi) { rem0 -= NB - bi; ++bi; }
  const int bj = bi + rem0;
  const bool diag = (bi == bj);

  const int tid  = threadIdx.x;
  const int lane = tid & 63;
  const int wid  = tid >> 6;
  const int wr   = wid >> 2;      // 0..1 : 64-row group
  const int wc   = wid & 3;       // 0..3 : 32-col group
  const int kg   = lane >> 5;
  const int r32  = lane & 31;

  // staging source decode (row-pair + granule-XOR map, R14 algebra, 512 thr):
  // granule g = tid: u = g>>3 (0..63), hc = (g&7)^(u&7),
  // srow = 2u + ((hc>>2)&1) in 0..127, scol = (hc&3)*16.
  const int hc   = (tid & 7) ^ ((tid >> 3) & 7);
  const int srow = 2 * (tid >> 3) + ((hc >> 2) & 1);   // 0..127
  const int scol = (hc & 3) * 16;
  const uint8_t* gA = Fb + (size_t)(bi * 128 + srow) * DDIM + scol;
  const uint8_t* gB = Fb + (size_t)(bj * 128 + srow) * DDIM + scol;
  uint8_t* ldsA = &As[0][0] + tid * 16;
  uint8_t* ldsB = &Bs[0][0] + tid * 16;

  // fragment read offsets (lo granule; hi = lo ^ 16) — R14 formulas
  int offA[2], offB1;
#pragma unroll
  for (int mt = 0; mt < 2; ++mt) {
    const int R = wr * 64 + mt * 32 + r32;
    const int u = R >> 1, h = R & 1;
    offA[mt] = u * 128 + (((h << 2) + 2 * kg) ^ (u & 7)) * 16;
  }
  {
    const int R = wc * 32 + r32;
    const int u = R >> 1, h = R & 1;
    offB1 = u * 128 + (((h << 2) + 2 * kg) ^ (u & 7)) * 16;
  }

  f32x16 acc[2] = {};

#define STAGE(kt2) do {                                                     \
    const int _sl = (kt2) % 3;                                              \
    gload16(gA + (kt2) * 64, ldsA + _sl * 8192);                            \
    gload16(gB + (kt2) * 64, ldsB + _sl * 8192);                            \
  } while (0)

  // prologue: K-tiles 0,1 in flight (4 loads); wait tile 0 (leave 2)
  STAGE(0); STAGE(1);
  asm volatile("s_waitcnt vmcnt(2)");
  __builtin_amdgcn_s_barrier();
  __builtin_amdgcn_sched_barrier(0);

#pragma unroll 1
  for (int kt = 0; kt < NKT; ++kt) {
    const uint8_t* sa = &As[0][0] + (kt % 3) * 8192;
    const uint8_t* sb = &Bs[0][0] + (kt % 3) * 8192;

    const i32x8 A0 = cat8(*(const i32x4*)(sa + offA[0]),
                          *(const i32x4*)(sa + (offA[0] ^ 16)));
    const i32x8 A1 = cat8(*(const i32x4*)(sa + offA[1]),
                          *(const i32x4*)(sa + (offA[1] ^ 16)));
    const i32x8 B0 = cat8(*(const i32x4*)(sb + offB1),
                          *(const i32x4*)(sb + (offB1 ^ 16)));

    if (kt + 2 < NKT) STAGE(kt + 2);

    acc[0] = __builtin_amdgcn_mfma_scale_f32_32x32x64_f8f6f4(
        A0, B0, acc[0], 0, 0, 0, SCL, 0, SCL);
    acc[1] = __builtin_amdgcn_mfma_scale_f32_32x32x64_f8f6f4(
        A1, B0, acc[1], 0, 0, 0, SCL, 0, SCL);

    if (kt + 2 < NKT)       asm volatile("s_waitcnt vmcnt(2)");  // kt+1 landed
    else if (kt == NKT - 2) asm volatile("s_waitcnt vmcnt(0)");
    if (kt < NKT - 1) {
      __builtin_amdgcn_s_barrier();
      __builtin_amdgcn_sched_barrier(0);   // next-iter ds_reads stay below
    }
  }

#undef STAGE

  // ---------- epilogue: triangle weights (32x32 C/D layout) ----------
  const int gj = bj * 128 + wc * 32 + r32;
  const float sqj = sq[gj], rnj = rn[gj];
  const int yj = y[gj];
  float lsum = 0.f;
#pragma unroll
  for (int mt = 0; mt < 2; ++mt) {
#pragma unroll
    for (int e = 0; e < 16; ++e) {
      const int gi = bi * 128 + wr * 64 + mt * 32 + (e & 3) + 8 * (e >> 2) + 4 * kg;
      const float g  = acc[mt][e];
      const float d2 = sq[gi] + sqj - 2.0f * g;
      const float dist = d2 > 0.f ? sqrtf(d2) : 0.f;
      const float sim  = g * rn[gi] * rnj;
      const float sgn  = (y[gi] == yj) ? 1.0f : -1.0f;
      float wgt;
      if (diag) wgt = (gj > gi) ? 2.0f : ((gj == gi) ? 1.0f : 0.0f);
      else      wgt = 2.0f;
      lsum += wgt * sgn * (dist - sim);
    }
  }
#pragma unroll
  for (int off = 32; off; off >>= 1) lsum += __shfl_down(lsum, off);
  if (lane == 0) wsum[wid] = lsum;
  __syncthreads();
  if (tid == 0) {
    float t = 0.f;
#pragma unroll
    for (int i = 0; i < 8; ++i) t += wsum[i];
    atomicAdd(out, t);
  }
}

extern "C" void kernel_launch(void* const* d_in, const int* in_sizes, int n_in,
                              void* d_out, int out_size, void* d_ws, size_t ws_size,
                              hipStream_t stream) {
  const float* F = (const float*)d_in[0];
  const int*   y = (const int*)d_in[1];
  float* out = (float*)d_out;

  uint8_t* Fb = (uint8_t*)d_ws;                               // 4 MB fp8
  float*  sq = (float*)((char*)d_ws + (size_t)NROWS * DDIM);
  float*  rn = sq + NROWS;

  prep_kernel<<<NROWS / 4, 256, 0, stream>>>(F, Fb, sq, rn, out);
  gram_kernel<<<NBLK, 512, 0, stream>>>(Fb, sq, rn, y, out);
}